// Round 4
// baseline (158.554 us; speedup 1.0000x reference)
//
#include <hip/hip_runtime.h>
#include <cstdint>

#define BATCH   8192
#define KDIM    256
#define HID     64
#define NODES   255
#define NPG     16    // nodes per block group

typedef unsigned short u16;
typedef unsigned int u32;
typedef short bf16x8 __attribute__((ext_vector_type(8)));
typedef float f32x16 __attribute__((ext_vector_type(16)));

// ---- helpers ---------------------------------------------------------------

__device__ __forceinline__ u32 f2bf(float f) {
  u32 u = __float_as_uint(f);
  return (u + 0x7FFFu + ((u >> 16) & 1u)) >> 16;
}

__device__ __forceinline__ void gld_lds16(const void* g, void* l) {
  // async global->LDS, 16B/lane; LDS dest = wave-uniform base + lane*16
  typedef __attribute__((address_space(1))) void* gp_t;
  typedef __attribute__((address_space(3))) void* lp_t;
  gp_t gp = reinterpret_cast<gp_t>(reinterpret_cast<uintptr_t>(g));
  lp_t lp = reinterpret_cast<lp_t>(static_cast<u32>(reinterpret_cast<uintptr_t>(l)));
  __builtin_amdgcn_global_load_lds(gp, lp, 16, 0, 0);
}

// ---- kernel 1: convert + pack ----------------------------------------------
// blocks [0,256):   x -> xpack (B-fragment granule order) via LDS transpose
// blocks [256,511): w1 -> w1pk, K-MAJOR granules (identity-copy staging order)
// blocks [511,575): w2/b1 -> wbp interleaved float2 in MFMA C/D register order

#define NPRM 16320     // 255*64

__global__ __launch_bounds__(256) void cvt_kernel(
    const float* __restrict__ x, const float* __restrict__ w1,
    const float* __restrict__ b1, const float* __restrict__ w2,
    u16* __restrict__ xpack, u16* __restrict__ w1pk,
    float2* __restrict__ wbp) {
  const int tid = threadIdx.x;
  const int blk = blockIdx.x;

  if (blk < 256) {
    __shared__ u16 sT[32 * 268];
    const float* xs = x + (size_t)blk * 32 * KDIM;
#pragma unroll
    for (int j = 0; j < 8; ++j) {
      int idx = j * 256 + tid;
      float4 v = ((const float4*)xs)[idx];
      int row = idx >> 6, f4 = idx & 63;
      *(u32*)&sT[row * 268 + f4 * 4]     = f2bf(v.x) | (f2bf(v.y) << 16);
      *(u32*)&sT[row * 268 + f4 * 4 + 2] = f2bf(v.z) | (f2bf(v.w) << 16);
    }
    __syncthreads();
#pragma unroll
    for (int j = 0; j < 4; ++j) {
      int d = j * 256 + tid;               // granule: ks*64 + hl*32 + l31
      int ks = d >> 6, hl = (d >> 5) & 1, l31 = d & 31;
      const u16* s8 = &sT[l31 * 268 + ks * 16 + hl * 8];
      u32 a = *(const u32*)s8, b = *(const u32*)(s8 + 2);
      u32 c = *(const u32*)(s8 + 4), e = *(const u32*)(s8 + 6);
      uint4 o = {a, b, c, e};
      ((uint4*)xpack)[(size_t)blk * 1024 + d] = o;
    }
  } else if (blk < 511) {
    __shared__ u16 sT[64 * 260];
    const int node = blk - 256;
    const float* src = w1 + (size_t)node * (HID * KDIM);
#pragma unroll
    for (int r = 0; r < 16; ++r) {
      int idx = r * 256 + tid;
      float4 v = ((const float4*)src)[idx];
      int h = idx >> 6, f4 = idx & 63;
      uint2 o;
      o.x = f2bf(v.x) | (f2bf(v.y) << 16);
      o.y = f2bf(v.z) | (f2bf(v.w) << 16);
      *(uint2*)&sT[h * 260 + f4 * 4] = o;
    }
    __syncthreads();
    u16* dst = w1pk + (size_t)node * (HID * KDIM);
#pragma unroll
    for (int r = 0; r < 8; ++r) {
      int g = r * 256 + tid;
      int kb = g >> 6, h = g & 63;
      const u16* s8 = &sT[h * 260 + kb * 8];
      uint2 lo = *(const uint2*)s8;
      uint2 hi = *(const uint2*)(s8 + 4);
      uint4 o = {lo.x, lo.y, hi.x, hi.y};
      ((uint4*)dst)[g] = o;
    }
  } else {
    int j = (blk - 511) * 256 + tid;
    if (j < NPRM) {
      int reg = j & 15, ht = (j >> 4) & 1, hl = (j >> 5) & 1, node = j >> 6;
      int h = ht * 32 + (reg & 3) + 8 * (reg >> 2) + 4 * hl;
      float2 v;
      v.x = w2[node * 64 + h];
      v.y = b1[node * 64 + h];
      wbp[j] = v;
    }
  }
}

// ---- kernel 2: fused MLP ---------------------------------------------------
// R12 = R11 with the OOB fix. R11 post-mortem: wq0/wq1 were [4] but indexed
// to [7] (each float4 = TWO float2 regs; 16 regs/half = 8 float4s) -> regs
// 8..15 used garbage w2/b1 -> absmax 4.3e-2. Structure unchanged:
// software-pipelined epilogue (T15): wave = 32 cols x 64 hid (xf[16]=64 regs),
// TWO acc banks (A/B, static names per rule #20). Node i's ks-loop interleaves
// 2 ds_read + 2 MFMA with 6 register-only VALU ops of node i-1's epilogue
// (w2/b1 hoisted to regs at node top -> no in-loop LDS). Epilogue VALU fills
// ds_read bubbles and overlaps the matrix pipe instead of following it.
// Block = 4 waves x 32 cols = 128 cols; grid 64x16; LDS 73.7KB -> 2 blocks/CU;
// regs ~220 -> still 2 waves/SIMD.

__global__ __launch_bounds__(256, 2) void fused_mlp_kernel(
    const u16* __restrict__ xpack,   // packed B-frag granules
    const u16* __restrict__ w1pk,    // [256(pad)][32 kb][64 h] granules
    const float2* __restrict__ wbp,  // [255][2 hl][2 ht][16] {w2,b1} permuted
    const float* __restrict__ b2,    // [255]
    float* __restrict__ no_t)        // [255][8192] node_outputs transposed
{
  __shared__ __align__(16) u16 sW[2][16384];       // 2 x 32 KB (full node)
  __shared__ __align__(16) float2 sWB[NPG * 64];   // 8 KB {w2,b1}

  const int tid  = threadIdx.x;
  const int lane = tid & 63;
  const int wv   = tid >> 6;
  const int l31  = lane & 31;
  const int hl   = lane >> 5;
  const int nbase = blockIdx.y * NPG;
  const int colBase = blockIdx.x * 128 + wv * 32;

  // stage one full node (2048 granules = 32 KB): identity copy
  auto stage_node = [&](int nodeIdx, int bufIdx) {
    const u16* base = w1pk + (size_t)nodeIdx * (HID * KDIM);
    char* lb = (char*)(&sW[bufIdx][0]);
#pragma unroll
    for (int j = 0; j < 8; ++j) {
      int s = j * 256 + tid;
      gld_lds16(base + s * 8, lb + s * 16);
    }
  };

  stage_node(nbase, 0);
  {
    const char* wsrc = (const char*)(wbp + (size_t)nbase * 64);
    gld_lds16(wsrc + tid * 16,        (char*)sWB + tid * 16);
    gld_lds16(wsrc + 4096 + tid * 16, (char*)sWB + 4096 + tid * 16);
  }

  // ---- x fragments: 1 col-tile of 32 cols x 16 ks, coalesced ----
  const int ctile = blockIdx.x * 4 + wv;
  bf16x8 xf[16];
  {
    const u16* src = xpack + (size_t)ctile * 8192 + lane * 8;
#pragma unroll
    for (int ks = 0; ks < 16; ++ks)
      xf[ks] = *(const bf16x8*)(src + ks * 512);
  }

  // lane's a-frag base: granule (kb = ks*2+hl, h = ht*32+l31)
  //   byte = ks*2048 + hl*1024 + ht*512 + l31*16
  const u32 abase = (u32)(hl * 64 + l31) * 16u;

  f32x16 accA0, accA1, accB0, accB1;

  __syncthreads();  // drains prologue staging vmcnt

  // NODE_STEP: compute node iN into banks (C0,C1); interleave epilogue of
  // node iN-1 from banks (P0,P1). Banks are STATIC names (rule #20).
  // wq0/wq1 are [8]: float4 q covers regs 2q,2q+1 -> regs 0..15.
#define NODE_STEP(C0, C1, P0, P1, doEpi, iN)                                   \
  {                                                                            \
    if ((iN) + 1 < NPG) stage_node(nbase + (iN) + 1, ((iN) + 1) & 1);          \
    C0 = (f32x16){0};                                                          \
    C1 = (f32x16){0};                                                          \
    const char* sw = (const char*)&sW[(iN) & 1][0] + abase;                    \
    float pacc = 0.f;                                                          \
    float4 wq0[8], wq1[8];                                                     \
    if (doEpi) {                                                               \
      const int wbo = ((iN) - 1) * 64 + hl * 32;                               \
      _Pragma("unroll")                                                        \
      for (int q = 0; q < 8; ++q) {                                            \
        wq0[q] = *(const float4*)&sWB[wbo + 2 * q];                            \
        wq1[q] = *(const float4*)&sWB[wbo + 16 + 2 * q];                       \
      }                                                                        \
    }                                                                          \
    _Pragma("unroll")                                                          \
    for (int ks = 0; ks < 16; ++ks) {                                          \
      bf16x8 a0 = *(const bf16x8*)(sw + ks * 2048);                            \
      bf16x8 a1 = *(const bf16x8*)(sw + ks * 2048 + 512);                      \
      C0 = __builtin_amdgcn_mfma_f32_32x32x16_bf16(a0, xf[ks], C0, 0, 0, 0);   \
      C1 = __builtin_amdgcn_mfma_f32_32x32x16_bf16(a1, xf[ks], C1, 0, 0, 0);   \
      if (doEpi) {                                                             \
        float4 q0 = wq0[ks >> 1], q1 = wq1[ks >> 1];                           \
        float w0 = (ks & 1) ? q0.z : q0.x, b0 = (ks & 1) ? q0.w : q0.y;        \
        float w1v = (ks & 1) ? q1.z : q1.x, b1v = (ks & 1) ? q1.w : q1.y;      \
        pacc += fmaxf(P0[ks] + b0, 0.f) * w0;                                  \
        pacc += fmaxf(P1[ks] + b1v, 0.f) * w1v;                                \
      }                                                                        \
    }                                                                          \
    if (doEpi) {                                                               \
      const int prvNode = nbase + (iN) - 1;                                    \
      pacc += __shfl_xor(pacc, 32);                                            \
      if (prvNode < NODES && hl == 0) {                                        \
        float sig = 1.0f / (1.0f + expf(-(pacc + b2[prvNode])));               \
        no_t[(size_t)prvNode * BATCH + colBase + l31] = sig;                   \
      }                                                                        \
    }                                                                          \
    __syncthreads();                                                           \
  }

  NODE_STEP(accA0, accA1, accB0, accB1, false, 0);          // node 0 -> A
#pragma unroll
  for (int ii = 1; ii <= 13; ii += 2) {
    NODE_STEP(accB0, accB1, accA0, accA1, true, ii);        // odd  -> B, epi A
    NODE_STEP(accA0, accA1, accB0, accB1, true, ii + 1);    // even -> A, epi B
  }
  NODE_STEP(accB0, accB1, accA0, accA1, true, 15);          // node 15 -> B

  // ---- drain: epilogue for node 15 (bank B) ----
  {
    const int node = nbase + 15;
    float pacc = 0.f;
    const int wbo = 15 * 64 + hl * 32;
#pragma unroll
    for (int ks = 0; ks < 16; ++ks) {
      float2 wb0 = sWB[wbo + ks];
      float2 wb1 = sWB[wbo + 16 + ks];
      pacc += fmaxf(accB0[ks] + wb0.y, 0.f) * wb0.x;
      pacc += fmaxf(accB1[ks] + wb1.y, 0.f) * wb1.x;
    }
    pacc += __shfl_xor(pacc, 32);
    if (node < NODES && hl == 0) {
      float sig = 1.0f / (1.0f + expf(-(pacc + b2[node])));
      no_t[(size_t)node * BATCH + colBase + l31] = sig;
    }
  }
#undef NODE_STEP
}

// ---- kernel 3: soft-decision-tree traversal --------------------------------

__global__ __launch_bounds__(256) void tree_kernel(
    const float* __restrict__ no_t,  // [255][8192]
    const float* __restrict__ leaf,  // [256]
    float* __restrict__ out)
{
  __shared__ float p[16][257];

  const int tid = threadIdx.x;
  const int bbase = blockIdx.x * 16;
  const int wave = tid >> 6;
  const int lane = tid & 63;

  for (int i = tid; i < NODES * 16; i += 256) {
    int n = i >> 4, r = i & 15;
    p[r][n] = no_t[(size_t)n * BATCH + bbase + r];
  }
  __syncthreads();

  float4 lw = ((const float4*)leaf)[lane];

  float* h_out  = out;
  float* pp_out = out + 8192;                            // [8192][256]
  float* no_out = out + 8192 + 8192 * 256;               // [8192][255]
  float* nr_out = out + 8192 + 8192 * 256 + 8192 * (size_t)NODES;  // [8192][255]

  for (int j = 0; j < 4; ++j) {
    const int r = wave * 4 + j;
    const int b = bbase + r;
    const float* pr = p[r];
    float* nr_b = nr_out + (size_t)b * NODES;

    float rc = 1.f;
#pragma unroll
    for (int L = 0; L < 6; ++L) {
      if (lane < (1 << L)) nr_b[(1 << L) - 1 + lane] = rc;
      float par = __shfl(rc, lane >> 1);
      float pv = pr[(1 << L) - 1 + (lane >> 1)];
      rc = par * ((lane & 1) ? pv : (1.f - pv));
    }
    nr_b[63 + lane] = rc;
    float p6 = pr[63 + lane];
    float r7a = rc * (1.f - p6), r7b = rc * p6;
    nr_b[127 + 2 * lane]     = r7a;
    nr_b[127 + 2 * lane + 1] = r7b;
    float p7a = pr[127 + 2 * lane], p7b = pr[127 + 2 * lane + 1];
    float4 pp;
    pp.x = r7a * (1.f - p7a);
    pp.y = r7a * p7a;
    pp.z = r7b * (1.f - p7b);
    pp.w = r7b * p7b;
    ((float4*)(pp_out + (size_t)b * 256))[lane] = pp;

    float* no_b = no_out + (size_t)b * NODES;
#pragma unroll
    for (int k = 0; k < 4; ++k) {
      int n = lane + 64 * k;
      if (n < NODES) no_b[n] = pr[n];
    }

    float hacc = pp.x * lw.x + pp.y * lw.y + pp.z * lw.z + pp.w * lw.w;
    hacc += __shfl_xor(hacc, 1);
    hacc += __shfl_xor(hacc, 2);
    hacc += __shfl_xor(hacc, 4);
    hacc += __shfl_xor(hacc, 8);
    hacc += __shfl_xor(hacc, 16);
    hacc += __shfl_xor(hacc, 32);
    if (lane == 0) h_out[b] = hacc;
  }
}

// ---- launcher --------------------------------------------------------------

extern "C" void kernel_launch(void* const* d_in, const int* in_sizes, int n_in,
                              void* d_out, int out_size, void* d_ws, size_t ws_size,
                              hipStream_t stream) {
  const float* x    = (const float*)d_in[0];
  const float* w1   = (const float*)d_in[1];
  const float* b1   = (const float*)d_in[2];
  const float* w2   = (const float*)d_in[3];
  const float* b2   = (const float*)d_in[4];
  const float* leaf = (const float*)d_in[5];
  float* out = (float*)d_out;

  // ws: xpack 4MB | w1pk 8MB (256-node pad; node 255 poison-but-finite) |
  //     wbp 128KB | no_t 8MB
  char* ws = (char*)d_ws;
  u16*    xpack = (u16*)ws;
  u16*    w1pk  = (u16*)(ws + (size_t)4194304);
  float2* wbp   = (float2*)(ws + (size_t)12582912);
  float*  no_t  = (float*)(ws + (size_t)12713472);

  cvt_kernel<<<575, 256, 0, stream>>>(x, w1, b1, w2, xpack, w1pk, wbp);

  dim3 g(64, 16);  // 64 col-blocks (128 cols) x 16 node-groups = 1024 blocks
  fused_mlp_kernel<<<g, 256, 0, stream>>>(xpack, w1pk, wbp, b2, no_t);

  tree_kernel<<<BATCH / 16, 256, 0, stream>>>(no_t, leaf, out);
}

// Round 6
// 153.945 us; speedup vs baseline: 1.0299x; 1.0299x over previous
//
#include <hip/hip_runtime.h>
#include <cstdint>

#define BATCH   8192
#define KDIM    256
#define HID     64
#define NODES   255
#define NPG     16    // nodes per block group

typedef unsigned short u16;
typedef unsigned int u32;
typedef short bf16x8 __attribute__((ext_vector_type(8)));
typedef float f32x16 __attribute__((ext_vector_type(16)));

// ---- helpers ---------------------------------------------------------------

__device__ __forceinline__ u32 f2bf(float f) {
  u32 u = __float_as_uint(f);
  return (u + 0x7FFFu + ((u >> 16) & 1u)) >> 16;
}

__device__ __forceinline__ void gld_lds16(const void* g, void* l) {
  // async global->LDS, 16B/lane; LDS dest = wave-uniform base + lane*16
  typedef __attribute__((address_space(1))) void* gp_t;
  typedef __attribute__((address_space(3))) void* lp_t;
  gp_t gp = reinterpret_cast<gp_t>(reinterpret_cast<uintptr_t>(g));
  lp_t lp = reinterpret_cast<lp_t>(static_cast<u32>(reinterpret_cast<uintptr_t>(l)));
  __builtin_amdgcn_global_load_lds(gp, lp, 16, 0, 0);
}

// ---- kernel 1: convert + pack ----------------------------------------------
// blocks [0,256):   x -> xpack (B-fragment granule order) via LDS transpose
// blocks [256,511): w1 -> w1pk, K-MAJOR granules: granule(node,kb,h) at
//                   node*2048 + kb*64 + h -> staging = identity copy
// blocks [511,639): w2/b1 permute into MFMA C/D register order
// (VERIFIED layout — identical to the R10/R12 passing rounds.)

#define NPRM 16320     // 255*64

__global__ __launch_bounds__(256) void cvt_kernel(
    const float* __restrict__ x, const float* __restrict__ w1,
    const float* __restrict__ b1, const float* __restrict__ w2,
    u16* __restrict__ xpack, u16* __restrict__ w1pk,
    float* __restrict__ b1p, float* __restrict__ w2p) {
  const int tid = threadIdx.x;
  const int blk = blockIdx.x;

  if (blk < 256) {
    __shared__ u16 sT[32 * 268];
    const float* xs = x + (size_t)blk * 32 * KDIM;
#pragma unroll
    for (int j = 0; j < 8; ++j) {
      int idx = j * 256 + tid;
      float4 v = ((const float4*)xs)[idx];
      int row = idx >> 6, f4 = idx & 63;
      *(u32*)&sT[row * 268 + f4 * 4]     = f2bf(v.x) | (f2bf(v.y) << 16);
      *(u32*)&sT[row * 268 + f4 * 4 + 2] = f2bf(v.z) | (f2bf(v.w) << 16);
    }
    __syncthreads();
#pragma unroll
    for (int j = 0; j < 4; ++j) {
      int d = j * 256 + tid;               // granule: ks*64 + hl*32 + l31
      int ks = d >> 6, hl = (d >> 5) & 1, l31 = d & 31;
      const u16* s8 = &sT[l31 * 268 + ks * 16 + hl * 8];
      u32 a = *(const u32*)s8, b = *(const u32*)(s8 + 2);
      u32 c = *(const u32*)(s8 + 4), e = *(const u32*)(s8 + 6);
      uint4 o = {a, b, c, e};
      ((uint4*)xpack)[(size_t)blk * 1024 + d] = o;
    }
  } else if (blk < 511) {
    __shared__ u16 sT[64 * 260];
    const int node = blk - 256;
    const float* src = w1 + (size_t)node * (HID * KDIM);
#pragma unroll
    for (int r = 0; r < 16; ++r) {
      int idx = r * 256 + tid;
      float4 v = ((const float4*)src)[idx];
      int h = idx >> 6, f4 = idx & 63;
      uint2 o;
      o.x = f2bf(v.x) | (f2bf(v.y) << 16);
      o.y = f2bf(v.z) | (f2bf(v.w) << 16);
      *(uint2*)&sT[h * 260 + f4 * 4] = o;
    }
    __syncthreads();
    u16* dst = w1pk + (size_t)node * (HID * KDIM);
#pragma unroll
    for (int r = 0; r < 8; ++r) {
      int g = r * 256 + tid;
      int kb = g >> 6, h = g & 63;
      const u16* s8 = &sT[h * 260 + kb * 8];
      uint2 lo = *(const uint2*)s8;
      uint2 hi = *(const uint2*)(s8 + 4);
      uint4 o = {lo.x, lo.y, hi.x, hi.y};
      ((uint4*)dst)[g] = o;
    }
  } else {
    int i2 = (blk - 511) * 256 + tid;
    if (i2 < 2 * NPRM) {
      int a = i2 >= NPRM;
      int j = a ? i2 - NPRM : i2;
      int reg = j & 15, rt = (j >> 4) & 1, hl = (j >> 5) & 1, node = j >> 6;
      int h = rt * 32 + (reg & 3) + 8 * (reg >> 2) + 4 * hl;
      float v = (a ? b1 : w2)[node * 64 + h];
      (a ? b1p : w2p)[j] = v;
    }
  }
}

// ---- kernel 2: fused MLP ---------------------------------------------------
// R14 = VERIFIED R10 structure (wave = 64 cols x 64 hid, 2x2 of 32x32, full-
// node 2x32KB dbuf, one barrier/node) + three same-direction trims:
//  1. Counted-vmcnt barrier: R10's __syncthreads drains vmcnt(0), which
//     includes the just-issued sigmoid global_store (~300-900 cyc) every
//     node. Only the 8 prefetch global_load_lds (issued BEFORE the store)
//     must drain; vmcnt retires in issue order, so s_waitcnt vmcnt(1) +
//     raw s_barrier lets the store float past the barrier.
//  2. Bias folded into acc init (acc = b1, not 0): -64 VALU adds/node/wave.
//  3. s_setprio(1) around the MFMA cluster: the 2 resident blocks/CU are
//     INDEPENDENT barrier groups (attn-like role diversity, m191 regime).
// R13 3-block occupancy attempt abandoned: register math (xf128+acc32+temps
// = 180 > 512/3) makes it spill-bound, and xf-reload variants blow X traffic
// 16-32x. 2 blocks/CU is the ceiling for this shape.

__global__ __launch_bounds__(256, 2) void fused_mlp_kernel(
    const u16* __restrict__ xpack,  // packed B-frag granules
    const u16* __restrict__ w1pk,   // [256(pad)][32 kb][64 h] granules
    const float* __restrict__ b1p,  // [255][2 hl][2 ht][16] permuted
    const float* __restrict__ w2p,  // [255][2 hl][2 ht][16] permuted
    const float* __restrict__ b2,   // [255]
    float* __restrict__ no_t)       // [255][8192] node_outputs transposed
{
  __shared__ __align__(16) u16 sW[2][16384];       // 2 x 32 KB (full node)
  __shared__ __align__(16) float sW2[NPG * 64];    // 4 KB
  __shared__ __align__(16) float sB1[NPG * 64];    // 4 KB

  const int tid  = threadIdx.x;
  const int lane = tid & 63;
  const int wv   = tid >> 6;
  const int l31  = lane & 31;
  const int hl   = lane >> 5;
  const int nbase = blockIdx.y * NPG;

  // stage one full node (2048 granules = 32 KB): identity copy
  auto stage_node = [&](int nodeIdx, int bufIdx) {
    const u16* base = w1pk + (size_t)nodeIdx * (HID * KDIM);
    char* lb = (char*)(&sW[bufIdx][0]);
#pragma unroll
    for (int j = 0; j < 8; ++j) {
      int s = j * 256 + tid;
      gld_lds16(base + s * 8, lb + s * 16);
    }
  };

  stage_node(nbase, 0);
  gld_lds16(w2p + (size_t)nbase * 64 + tid * 4, (char*)sW2 + tid * 16);
  gld_lds16(b1p + (size_t)nbase * 64 + tid * 4, (char*)sB1 + tid * 16);

  // ---- x fragments: 2 col-tiles of 32 x 16 ks, coalesced ----
  const int ctile0 = blockIdx.x * 8 + wv * 2;
  bf16x8 xf[2][16];
#pragma unroll
  for (int ct = 0; ct < 2; ++ct) {
    const u16* src = xpack + ((size_t)(ctile0 + ct) * 16) * 512 + lane * 8;
#pragma unroll
    for (int ks = 0; ks < 16; ++ks)
      xf[ct][ks] = *(const bf16x8*)(src + ks * 512);
  }

  // lane's a-frag base: granule (kb = ks*2+hl, h = ht*32+l31)
  //   byte = ks*2048 + hl*1024 + ht*512 + l31*16
  const u32 abase = (u32)(hl * 64 + l31) * 16u;

  __syncthreads();  // drains prologue staging vmcnt (full drain, once)
  int buf = 0;

  for (int i = 0; i < NPG; ++i) {
    const int node = nbase + i;

    // prefetch next node a FULL iteration ahead; its target buffer was last
    // read before the PREVIOUS barrier -> race-free. These 8 gld_lds are the
    // OLDEST vmcnt ops of this iteration (issued before the store below).
    if (i + 1 < NPG) stage_node(nbase + i + 1, buf ^ 1);

    // ---- acc init from bias (fold): saves the epilogue bias adds ----
    f32x16 acc00, acc01, acc10, acc11;
    {
      const int o0 = i * 64 + hl * 32;
#pragma unroll
      for (int qd = 0; qd < 4; ++qd) {
        float4 b0 = *(const float4*)&sB1[o0 + qd * 4];         // ht=0 rows
        float4 b1q = *(const float4*)&sB1[o0 + 16 + qd * 4];   // ht=1 rows
#pragma unroll
        for (int e = 0; e < 4; ++e) {
          acc00[qd * 4 + e] = (&b0.x)[e];
          acc01[qd * 4 + e] = (&b0.x)[e];
          acc10[qd * 4 + e] = (&b1q.x)[e];
          acc11[qd * 4 + e] = (&b1q.x)[e];
        }
      }
    }

    const char* sw = (const char*)&sW[buf][0] + abase;
    __builtin_amdgcn_s_setprio(1);
#pragma unroll
    for (int ks = 0; ks < 16; ++ks) {
      bf16x8 a0 = *(const bf16x8*)(sw + ks * 2048);        // ht=0
      bf16x8 a1 = *(const bf16x8*)(sw + ks * 2048 + 512);  // ht=1
      acc00 = __builtin_amdgcn_mfma_f32_32x32x16_bf16(a0, xf[0][ks], acc00, 0, 0, 0);
      acc01 = __builtin_amdgcn_mfma_f32_32x32x16_bf16(a0, xf[1][ks], acc01, 0, 0, 0);
      acc10 = __builtin_amdgcn_mfma_f32_32x32x16_bf16(a1, xf[0][ks], acc10, 0, 0, 0);
      acc11 = __builtin_amdgcn_mfma_f32_32x32x16_bf16(a1, xf[1][ks], acc11, 0, 0, 0);
    }
    __builtin_amdgcn_s_setprio(0);

    // ---- epilogue: full logit, wave-local (bias already in acc) ----
    float p0 = 0.f, p1 = 0.f;
#pragma unroll
    for (int qd = 0; qd < 4; ++qd) {
      int o = i * 64 + hl * 32 + qd * 4;
      float4 w0 = *(const float4*)&sW2[o];         // ht=0
      float4 w1q = *(const float4*)&sW2[o + 16];   // ht=1
#pragma unroll
      for (int e = 0; e < 4; ++e) {
        int r = qd * 4 + e;
        float w0e = (&w0.x)[e];
        float w1e = (&w1q.x)[e];
        p0 += fmaxf(acc00[r], 0.f) * w0e;
        p1 += fmaxf(acc01[r], 0.f) * w0e;
        p0 += fmaxf(acc10[r], 0.f) * w1e;
        p1 += fmaxf(acc11[r], 0.f) * w1e;
      }
    }
    // each lane held rows with its hl; partner lane^32 has the other half
    p0 += __shfl_xor(p0, 32);
    p1 += __shfl_xor(p1, 32);

    if (node < NODES) {
      // col = wv*64 + hl*32 + l31 = wv*64 + lane; hl=0 stores col-half 0
      float pv = hl ? p1 : p0;
      float sig = 1.0f / (1.0f + expf(-(pv + b2[node])));
      no_t[(size_t)node * BATCH + blockIdx.x * 256 + wv * 64 + lane] = sig;
    }

    // Counted barrier: drain the 8 prefetch gld_lds (oldest) but let the
    // sigmoid store (newest vmcnt op) float past the barrier. vmcnt retires
    // in issue order, so vmcnt(1) == "all but the store are done".
    asm volatile("s_waitcnt vmcnt(1)" ::: "memory");
    __builtin_amdgcn_s_barrier();
    __builtin_amdgcn_sched_barrier(0);

    buf ^= 1;
  }
}

// ---- kernel 3: soft-decision-tree traversal --------------------------------

__global__ __launch_bounds__(256) void tree_kernel(
    const float* __restrict__ no_t,  // [255][8192]
    const float* __restrict__ leaf,  // [256]
    float* __restrict__ out)
{
  __shared__ float p[16][257];

  const int tid = threadIdx.x;
  const int bbase = blockIdx.x * 16;
  const int wave = tid >> 6;
  const int lane = tid & 63;

  for (int i = tid; i < NODES * 16; i += 256) {
    int n = i >> 4, r = i & 15;
    p[r][n] = no_t[(size_t)n * BATCH + bbase + r];
  }
  __syncthreads();

  float4 lw = ((const float4*)leaf)[lane];

  float* h_out  = out;
  float* pp_out = out + 8192;                            // [8192][256]
  float* no_out = out + 8192 + 8192 * 256;               // [8192][255]
  float* nr_out = out + 8192 + 8192 * 256 + 8192 * (size_t)NODES;  // [8192][255]

  for (int j = 0; j < 4; ++j) {
    const int r = wave * 4 + j;
    const int b = bbase + r;
    const float* pr = p[r];
    float* nr_b = nr_out + (size_t)b * NODES;

    float rc = 1.f;
#pragma unroll
    for (int L = 0; L < 6; ++L) {
      if (lane < (1 << L)) nr_b[(1 << L) - 1 + lane] = rc;
      float par = __shfl(rc, lane >> 1);
      float pv = pr[(1 << L) - 1 + (lane >> 1)];
      rc = par * ((lane & 1) ? pv : (1.f - pv));
    }
    nr_b[63 + lane] = rc;
    float p6 = pr[63 + lane];
    float r7a = rc * (1.f - p6), r7b = rc * p6;
    nr_b[127 + 2 * lane]     = r7a;
    nr_b[127 + 2 * lane + 1] = r7b;
    float p7a = pr[127 + 2 * lane], p7b = pr[127 + 2 * lane + 1];
    float4 pp;
    pp.x = r7a * (1.f - p7a);
    pp.y = r7a * p7a;
    pp.z = r7b * (1.f - p7b);
    pp.w = r7b * p7b;
    ((float4*)(pp_out + (size_t)b * 256))[lane] = pp;

    float* no_b = no_out + (size_t)b * NODES;
#pragma unroll
    for (int k = 0; k < 4; ++k) {
      int n = lane + 64 * k;
      if (n < NODES) no_b[n] = pr[n];
    }

    float hacc = pp.x * lw.x + pp.y * lw.y + pp.z * lw.z + pp.w * lw.w;
    hacc += __shfl_xor(hacc, 1);
    hacc += __shfl_xor(hacc, 2);
    hacc += __shfl_xor(hacc, 4);
    hacc += __shfl_xor(hacc, 8);
    hacc += __shfl_xor(hacc, 16);
    hacc += __shfl_xor(hacc, 32);
    if (lane == 0) h_out[b] = hacc;
  }
}

// ---- launcher --------------------------------------------------------------

extern "C" void kernel_launch(void* const* d_in, const int* in_sizes, int n_in,
                              void* d_out, int out_size, void* d_ws, size_t ws_size,
                              hipStream_t stream) {
  const float* x    = (const float*)d_in[0];
  const float* w1   = (const float*)d_in[1];
  const float* b1   = (const float*)d_in[2];
  const float* w2   = (const float*)d_in[3];
  const float* b2   = (const float*)d_in[4];
  const float* leaf = (const float*)d_in[5];
  float* out = (float*)d_out;

  // ws: xpack 4MB | w1pk 8MB (256-node pad; node 255 poison-but-finite) |
  //     w2p 64KB | b1p 64KB | no_t 8MB
  char* ws = (char*)d_ws;
  u16*   xpack = (u16*)ws;
  u16*   w1pk  = (u16*)(ws + (size_t)4194304);
  float* w2p   = (float*)(ws + (size_t)12582912);
  float* b1p   = (float*)(ws + (size_t)12648192);
  float* no_t  = (float*)(ws + (size_t)12713472);

  cvt_kernel<<<639, 256, 0, stream>>>(x, w1, b1, w2, xpack, w1pk, b1p, w2p);

  dim3 g(32, 16);  // 32 col-blocks (256 cols) x 16 node-groups = 512 blocks
  fused_mlp_kernel<<<g, 256, 0, stream>>>(xpack, w1pk, b1p, w2p, b2, no_t);

  tree_kernel<<<BATCH / 16, 256, 0, stream>>>(no_t, leaf, out);
}